// Round 6
// baseline (40.423 us; speedup 1.0000x reference)
//
#include <hip/hip_runtime.h>
#include <cfloat>

// DistLoss: out = sum_m min_{s,n} ||surfaces[s,n,:] - targets[m,:]||^2
// surfaces: [4,4096,3] f32 (flat SN=16384), targets: [16384,3] f32.
//
// R6: k1 is VALU-ISSUE-bound at the sustained clock (~1.6 GHz, m07).
// Cut inst/pair 4.8 -> ~2.5 with packed fp32 (v_pk_fma_f32, VOP3P):
// 2 targets per packed register pair. d_pk = pkfma(x, tx_pk,
// pkfma(y, ty_pk, pkfma(z, tz_pk, {s2,s2}))); min3 on unpacked halves.
// Ping-pong A/B point registers (loads land in the set just consumed ->
// no copy movs). LDS broadcast float4(x,y,z,s2) as before.
//
//  k1: grid (8,128), 256 thr, T=8 targets (4 packed pairs), CHUNK=128.
//  k2: 256 blocks x 256 thr: min over 128 chunks, block-sum -> part[256];
//      last block (atomic election) reduces part -> out[0].
// Fixed-order reductions -> deterministic.

namespace {
constexpr int M   = 16384;
constexpr int SN  = 16384;
constexpr int TPB = 256;
constexpr int T   = 8;                     // targets per thread (4 packed pairs)
constexpr int Q   = T / 2;
constexpr int TGT_PER_BLOCK = TPB * T;     // 2048
constexpr int NCHUNK = 128;
constexpr int CHUNK  = SN / NCHUNK;        // 128 points
constexpr int K2B    = 256;
}

typedef float v2f __attribute__((ext_vector_type(2)));

static __device__ __forceinline__ v2f pkfma(float a, v2f b, v2f c) {
  v2f av; av.x = a; av.y = a;
  return __builtin_elementwise_fma(av, b, c);
}
static __device__ __forceinline__ float min3f(float a, float b, float c) {
  return fminf(fminf(a, b), c);
}

__global__ __launch_bounds__(TPB, 4) void dist_partial_min(
    const float* __restrict__ surf,   // [SN][3]
    const float* __restrict__ tgt,    // [M][3]
    float* __restrict__ wmin,         // [NCHUNK][M]
    unsigned* __restrict__ counter)
{
  __shared__ alignas(16) float4 spt[CHUNK];   // (x, y, z, s2)

  const int tid   = threadIdx.x;
  const int mbase = blockIdx.x * TGT_PER_BLOCK;
  const int cbase = blockIdx.y * CHUNK;

  if (blockIdx.x == 0 && blockIdx.y == 0 && tid == 0) counter[0] = 0u;

  if (tid < CHUNK) {
    const float* s = surf + (size_t)(cbase + tid) * 3;
    const float x = s[0], y = s[1], z = s[2];
    spt[tid] = make_float4(x, y, z, fmaf(x, x, fmaf(y, y, z * z)));
  }

  // packed targets: pair q holds targets j=2q (lo) and j=2q+1 (hi)
  v2f txp[Q], typ[Q], tzp[Q], b2p[Q];
  float mnl[Q], mnh[Q];
#pragma unroll
  for (int q = 0; q < Q; ++q) {
#pragma unroll
    for (int h = 0; h < 2; ++h) {
      const int m     = mbase + (2 * q + h) * TPB + tid;
      const float* tp = tgt + (size_t)m * 3;
      const float a = tp[0], b = tp[1], c = tp[2];
      if (h == 0) { txp[q].x = -2.0f*a; typ[q].x = -2.0f*b; tzp[q].x = -2.0f*c;
                    b2p[q].x = fmaf(a,a,fmaf(b,b,c*c)); }
      else        { txp[q].y = -2.0f*a; typ[q].y = -2.0f*b; tzp[q].y = -2.0f*c;
                    b2p[q].y = fmaf(a,a,fmaf(b,b,c*c)); }
    }
    mnl[q] = FLT_MAX; mnh[q] = FLT_MAX;
  }
  __syncthreads();

  float4 A0 = spt[0], A1 = spt[1], A2 = spt[2], A3 = spt[3];
  float4 B0, B1, B2, B3;

#define COMPUTE4(P0, P1, P2, P3)                                          \
  {                                                                       \
    _Pragma("unroll")                                                     \
    for (int q = 0; q < Q; ++q) {                                         \
      v2f s0; s0.x = P0.w; s0.y = P0.w;                                   \
      v2f s1; s1.x = P1.w; s1.y = P1.w;                                   \
      v2f s2; s2.x = P2.w; s2.y = P2.w;                                   \
      v2f s3; s3.x = P3.w; s3.y = P3.w;                                   \
      v2f d0 = pkfma(P0.x, txp[q], pkfma(P0.y, typ[q], pkfma(P0.z, tzp[q], s0))); \
      v2f d1 = pkfma(P1.x, txp[q], pkfma(P1.y, typ[q], pkfma(P1.z, tzp[q], s1))); \
      v2f d2 = pkfma(P2.x, txp[q], pkfma(P2.y, typ[q], pkfma(P2.z, tzp[q], s2))); \
      v2f d3 = pkfma(P3.x, txp[q], pkfma(P3.y, typ[q], pkfma(P3.z, tzp[q], s3))); \
      mnl[q] = min3f(mnl[q], d0.x, d1.x);                                 \
      mnh[q] = min3f(mnh[q], d0.y, d1.y);                                 \
      mnl[q] = min3f(mnl[q], d2.x, d3.x);                                 \
      mnh[q] = min3f(mnh[q], d2.y, d3.y);                                 \
    }                                                                     \
  }

  for (int p = 0; p < CHUNK; p += 8) {
    B0 = spt[p + 4]; B1 = spt[p + 5]; B2 = spt[p + 6]; B3 = spt[p + 7];
    COMPUTE4(A0, A1, A2, A3);
    const int pn = (p + 8) & (CHUNK - 1);   // wraps on last iter (values unused)
    A0 = spt[pn + 0]; A1 = spt[pn + 1]; A2 = spt[pn + 2]; A3 = spt[pn + 3];
    COMPUTE4(B0, B1, B2, B3);
  }
#undef COMPUTE4

#pragma unroll
  for (int q = 0; q < Q; ++q) {
    wmin[(size_t)blockIdx.y * M + mbase + (2*q+0) * TPB + tid] = mnl[q] + b2p[q].x;
    wmin[(size_t)blockIdx.y * M + mbase + (2*q+1) * TPB + tid] = mnh[q] + b2p[q].y;
  }
}

__global__ __launch_bounds__(256) void dist_min_sum(
    const float* __restrict__ wmin,   // [NCHUNK][M]
    float* __restrict__ part,         // [K2B]
    unsigned* __restrict__ counter,
    float* __restrict__ out)
{
  const int tid  = threadIdx.x;
  const int lane = tid & 63;
  const int w    = tid >> 6;                 // wave 0..3 -> chunk quarter
  const int m    = blockIdx.x * 64 + lane;

  float mnv = FLT_MAX;
  const int c0 = w * (NCHUNK / 4);
#pragma unroll 8
  for (int c = 0; c < NCHUNK / 4; ++c)
    mnv = fminf(mnv, wmin[(size_t)(c0 + c) * M + m]);

  __shared__ float red[4][64];
  red[w][lane] = mnv;
  __syncthreads();

  if (w == 0) {
    float v = fminf(fminf(red[0][lane], red[1][lane]),
                    fminf(red[2][lane], red[3][lane]));
    for (int off = 32; off; off >>= 1) v += __shfl_down(v, off, 64);

    unsigned done = 0;
    if (lane == 0) {
      part[blockIdx.x] = v;
      __threadfence();
      done = atomicAdd(counter, 1u);
    }
    done = __shfl(done, 0, 64);

    if (done == (unsigned)(K2B - 1)) {        // last block finalizes
      __threadfence();
      float s = 0.0f;
#pragma unroll
      for (int i = 0; i < K2B / 64; ++i) s += part[i * 64 + lane];
      for (int off = 32; off; off >>= 1) s += __shfl_down(s, off, 64);
      if (lane == 0) out[0] = s;
    }
  }
}

extern "C" void kernel_launch(void* const* d_in, const int* in_sizes, int n_in,
                              void* d_out, int out_size, void* d_ws, size_t ws_size,
                              hipStream_t stream) {
  const float* surf = (const float*)d_in[0];   // 4*4096*3
  const float* tgt  = (const float*)d_in[1];   // 16384*3
  float* out = (float*)d_out;

  float*    wmin    = (float*)d_ws;                        // NCHUNK*M f32 = 8 MB
  float*    part    = wmin + (size_t)NCHUNK * M;           // K2B floats
  unsigned* counter = (unsigned*)(part + K2B);             // 1 u32

  dim3 g1(M / TGT_PER_BLOCK, NCHUNK);
  dist_partial_min<<<g1, TPB, 0, stream>>>(surf, tgt, wmin, counter);
  dist_min_sum<<<K2B, 256, 0, stream>>>(wmin, part, counter, out);
}

// Round 7
// 40.393 us; speedup vs baseline: 1.0007x; 1.0007x over previous
//
#include <hip/hip_runtime.h>
#include <cfloat>

// DistLoss: out = sum_m min_{s,n} ||surfaces[s,n,:] - targets[m,:]||^2
// surfaces: [4,4096,3] f32 (flat SN=16384), targets: [16384,3] f32.
//
// R7: MFMA (16x16x32 bf16) with split-bf16 precision.
//   dist(p,m) = sum_k A[p,k]*B[k,m], K-slots (11 used, 21 zero):
//     per coord c: A=(hi,hi,lo) x B=(hi,lo,hi)  -> hi*hi + hi*lo + lo*hi
//     s2:          A=(s2_hi,s2_lo) x B=(1,1)
//   b2[m] added after the min (constant per target).
//  k0: build A_exp[SN][32], B_exp[M][32] (bf16), b2f[M]; reset counter.
//  k1: 1024 blocks x 4 waves. Each wave: 8 B-frags in regs (128 targets),
//      streams 512 points (32 A-tiles, reg-prefetched from L2), 8 mfma +
//      min3 per tile; cross-lane min (xor 16,32); writes wmin[c][128 tgts].
//  k2: 256 blocks: min over 32 chunks + b2, wave-sum -> part[256];
//      last block (election) sums part -> out. Fixed order -> deterministic.

namespace {
constexpr int M   = 16384;
constexpr int SN  = 16384;
constexpr int NCH = 32;           // point chunks
constexpr int PPC = SN / NCH;     // 512 points per chunk
constexpr int NG  = 128;          // target groups
constexpr int TPG = 128;          // targets per group (8 frags x 16)
constexpr int K2B = 256;
}

typedef short bf16x8 __attribute__((ext_vector_type(8)));
typedef float f32x4  __attribute__((ext_vector_type(4)));

static __device__ __forceinline__ unsigned short f2bf(float f) {
  unsigned int u = __builtin_bit_cast(unsigned int, f);
  return (unsigned short)((u + 0x7FFFu + ((u >> 16) & 1u)) >> 16);
}
static __device__ __forceinline__ float bf2f(unsigned short h) {
  unsigned int u = ((unsigned int)h) << 16;
  return __builtin_bit_cast(float, u);
}

__global__ __launch_bounds__(256) void build_ab(
    const float* __restrict__ surf, const float* __restrict__ tgt,
    unsigned short* __restrict__ Aex, unsigned short* __restrict__ Bex,
    float* __restrict__ b2f, unsigned* __restrict__ counter)
{
  const int i = blockIdx.x * 256 + threadIdx.x;
  if (i == 0) counter[0] = 0u;

  {  // A row: point i
    const float x = surf[(size_t)i*3+0], y = surf[(size_t)i*3+1], z = surf[(size_t)i*3+2];
    const float s2 = fmaf(x, x, fmaf(y, y, z * z));
    unsigned short row[32];
#pragma unroll
    for (int k = 0; k < 32; ++k) row[k] = 0;
    const float cs[3] = {x, y, z};
#pragma unroll
    for (int c = 0; c < 3; ++c) {
      const unsigned short hi = f2bf(cs[c]);
      const unsigned short lo = f2bf(cs[c] - bf2f(hi));
      row[3*c+0] = hi; row[3*c+1] = hi; row[3*c+2] = lo;
    }
    const unsigned short shi = f2bf(s2);
    const unsigned short slo = f2bf(s2 - bf2f(shi));
    row[9] = shi; row[10] = slo;
#pragma unroll
    for (int k = 0; k < 16; ++k)
      ((unsigned int*)(Aex + (size_t)i*32))[k] =
          (unsigned int)row[2*k] | ((unsigned int)row[2*k+1] << 16);
  }
  {  // B row: target i
    const float a = tgt[(size_t)i*3+0], b = tgt[(size_t)i*3+1], c = tgt[(size_t)i*3+2];
    b2f[i] = fmaf(a, a, fmaf(b, b, c * c));
    const float us[3] = {-2.0f*a, -2.0f*b, -2.0f*c};
    unsigned short row[32];
#pragma unroll
    for (int k = 0; k < 32; ++k) row[k] = 0;
#pragma unroll
    for (int q = 0; q < 3; ++q) {
      const unsigned short hi = f2bf(us[q]);
      const unsigned short lo = f2bf(us[q] - bf2f(hi));
      row[3*q+0] = hi; row[3*q+1] = lo; row[3*q+2] = hi;
    }
    const unsigned short one = f2bf(1.0f);
    row[9] = one; row[10] = one;
#pragma unroll
    for (int k = 0; k < 16; ++k)
      ((unsigned int*)(Bex + (size_t)i*32))[k] =
          (unsigned int)row[2*k] | ((unsigned int)row[2*k+1] << 16);
  }
}

__global__ __launch_bounds__(256, 4) void dist_mfma(
    const unsigned short* __restrict__ Aex,
    const unsigned short* __restrict__ Bex,
    float* __restrict__ wmin)          // [NCH][M]
{
  const int tid  = threadIdx.x;
  const int lane = tid & 63;
  const int wid  = tid >> 6;
  const int wg   = blockIdx.x * 4 + wid;     // 0..4095
  const int g    = wg & (NG - 1);            // target group 0..127
  const int c    = wg >> 7;                  // point chunk 0..31
  const int m0   = g * TPG;
  const int r15  = lane & 15;
  const int koff = (lane >> 4) * 8;          // k-slice of 8 bf16

  // 8 B fragments: targets m0 + f*16 + r15, k-slice koff
  bf16x8 bfr[8];
#pragma unroll
  for (int f = 0; f < 8; ++f)
    bfr[f] = *(const bf16x8*)(Bex + ((size_t)(m0 + f*16 + r15)) * 32 + koff);

  float mn[8];
#pragma unroll
  for (int f = 0; f < 8; ++f) mn[f] = FLT_MAX;

  const int pbase = c * PPC;
  const unsigned short* ap = Aex + ((size_t)(pbase + r15)) * 32 + koff;

  bf16x8 acur = *(const bf16x8*)ap;
  for (int r = 0; r < PPC / 16; ++r) {
    const int rn = (r + 1 < PPC / 16) ? r + 1 : r;     // last iter: dummy reload
    const bf16x8 anxt = *(const bf16x8*)(ap + (size_t)rn * 16 * 32);
#pragma unroll
    for (int f = 0; f < 8; ++f) {
      const f32x4 d = __builtin_amdgcn_mfma_f32_16x16x32_bf16(
          acur, bfr[f], (f32x4){0.f, 0.f, 0.f, 0.f}, 0, 0, 0);
      mn[f] = fminf(fminf(mn[f], fminf(d[0], d[1])), fminf(d[2], d[3]));
    }
    acur = anxt;
  }

  // combine the 4 row-groups (lane ^ 16, lane ^ 32)
#pragma unroll
  for (int f = 0; f < 8; ++f) {
    float v = mn[f];
    v = fminf(v, __shfl_xor(v, 16, 64));
    v = fminf(v, __shfl_xor(v, 32, 64));
    mn[f] = v;
  }
  if (lane < 16) {
#pragma unroll
    for (int f = 0; f < 8; ++f)
      wmin[(size_t)c * M + m0 + f * 16 + lane] = mn[f];
  }
}

__global__ __launch_bounds__(256) void dist_min_sum(
    const float* __restrict__ wmin,   // [NCH][M]
    const float* __restrict__ b2f,    // [M]
    float* __restrict__ part,         // [K2B]
    unsigned* __restrict__ counter,
    float* __restrict__ out)
{
  const int tid  = threadIdx.x;
  const int lane = tid & 63;
  const int w    = tid >> 6;                 // wave 0..3 -> 8 chunks each
  const int m    = blockIdx.x * 64 + lane;

  float mnv = FLT_MAX;
  const int c0 = w * (NCH / 4);
#pragma unroll
  for (int ci = 0; ci < NCH / 4; ++ci)
    mnv = fminf(mnv, wmin[(size_t)(c0 + ci) * M + m]);

  __shared__ float red[4][64];
  red[w][lane] = mnv;
  __syncthreads();

  if (w == 0) {
    float v = fminf(fminf(red[0][lane], red[1][lane]),
                    fminf(red[2][lane], red[3][lane]));
    v += b2f[m];
    for (int off = 32; off; off >>= 1) v += __shfl_down(v, off, 64);

    unsigned done = 0;
    if (lane == 0) {
      part[blockIdx.x] = v;
      __threadfence();
      done = atomicAdd(counter, 1u);
    }
    done = __shfl(done, 0, 64);

    if (done == (unsigned)(K2B - 1)) {        // last block finalizes
      __threadfence();
      float s = 0.0f;
#pragma unroll
      for (int i = 0; i < K2B / 64; ++i) s += part[i * 64 + lane];
      for (int off = 32; off; off >>= 1) s += __shfl_down(s, off, 64);
      if (lane == 0) out[0] = s;
    }
  }
}

extern "C" void kernel_launch(void* const* d_in, const int* in_sizes, int n_in,
                              void* d_out, int out_size, void* d_ws, size_t ws_size,
                              hipStream_t stream) {
  const float* surf = (const float*)d_in[0];   // 4*4096*3
  const float* tgt  = (const float*)d_in[1];   // 16384*3
  float* out = (float*)d_out;

  unsigned short* Aex = (unsigned short*)d_ws;             // SN*32*2  = 1 MB
  unsigned short* Bex = Aex + (size_t)SN * 32;             // M*32*2   = 1 MB
  float* b2f  = (float*)(Bex + (size_t)M * 32);            // M*4      = 64 KB
  float* wmin = b2f + M;                                   // NCH*M*4  = 2 MB
  float* part = wmin + (size_t)NCH * M;                    // K2B*4
  unsigned* counter = (unsigned*)(part + K2B);             // 4 B

  build_ab<<<SN / 256, 256, 0, stream>>>(surf, tgt, Aex, Bex, b2f, counter);
  dist_mfma<<<(NG * NCH) / 4, 256, 0, stream>>>(Aex, Bex, wmin);
  dist_min_sum<<<K2B, 256, 0, stream>>>(wmin, b2f, part, counter, out);
}